// Round 17
// baseline (286.097 us; speedup 1.0000x reference)
//
#include <hip/hip_runtime.h>
#include <hip/hip_bf16.h>

#define BATCH 8
#define CHN 256
#define HWN 16384
#define EPSV 1e-6f
#define ESCH 32

typedef __attribute__((ext_vector_type(8))) short bf16x8;
typedef __attribute__((ext_vector_type(4))) short s16x4;
typedef __attribute__((ext_vector_type(4))) float f32x4;
typedef __hip_bfloat16 bf16;

__device__ __forceinline__ short f2s(float f){
  union { bf16 h; short s; } u; u.h = __float2bfloat16(f); return u.s;
}
__device__ __forceinline__ float s2f(short s){
  union { unsigned u; float f; } v; v.u = ((unsigned)(unsigned short)s) << 16; return v.f;
}
__device__ __forceinline__ void gload16(const bf16* g, bf16* l){
  __builtin_amdgcn_global_load_lds((const __attribute__((address_space(1))) void*)g,
                                   (__attribute__((address_space(3))) void*)l, 16, 0, 0);
}

// ---- K1 v7: read x once: GN stats + transpose x^T -> bf16 -------------------
// Half-c blocks [128 c][64 n]: 16.5 KB LDS -> 8 blocks/CU (2x TLP for a
// latency-bound kernel). Swizzle key (row&15)<<4: 16 keys/wave-instr.
__global__ __launch_bounds__(256) void xstats_t(const float* __restrict__ x,
    bf16* __restrict__ xt, float* __restrict__ pst){
  int b = blockIdx.z, chh = blockIdx.y, n0 = blockIdx.x * 64;
  __shared__ char scr[64 * 256];              // [n][c' bf16], 16 KB swizzled
  __shared__ float sg[16], ssg[16];
  int t = threadIdx.x, lane = t & 63, w = t >> 6;
  if (t < 16){ sg[t] = 0.f; ssg[t] = 0.f; }
  __syncthreads();
  const float* xb = x + (size_t)b * CHN * HWN + (size_t)(chh * 128) * HWN
                    + n0 + (t & 15) * 4;
  int c0 = t >> 4;                            // 0..15
  #pragma unroll
  for (int i = 0; i < 8; i++){
    int cl = i * 16 + c0;                     // 0..127 local c
    float4 v = *(const float4*)(xb + (size_t)cl * HWN);
    int nf = (t & 15) * 4;
    #pragma unroll
    for (int j = 0; j < 4; j++){
      int row = nf + j;
      float e = j == 0 ? v.x : (j == 1 ? v.y : (j == 2 ? v.z : v.w));
      *(short*)(scr + row * 256 + ((cl * 2) ^ ((row & 15) << 4))) = f2s(e);
    }
    float s  = v.x + v.y + v.z + v.w;
    float ss = v.x*v.x + v.y*v.y + v.z*v.z + v.w*v.w;
    s  += __shfl_xor(s, 1);  s  += __shfl_xor(s, 2);  s  += __shfl_xor(s, 4);
    s  += __shfl_xor(s, 8);  s  += __shfl_xor(s, 16); s  += __shfl_xor(s, 32);
    ss += __shfl_xor(ss, 1); ss += __shfl_xor(ss, 2); ss += __shfl_xor(ss, 4);
    ss += __shfl_xor(ss, 8); ss += __shfl_xor(ss, 16); ss += __shfl_xor(ss, 32);
    if (lane == 0){                           // wave's 4 cl all in group i*2+(w>>1)
      atomicAdd(&sg[i * 2 + (w >> 1)], s);
      atomicAdd(&ssg[i * 2 + (w >> 1)], ss);
    }
  }
  __syncthreads();
  if (t < 16){
    atomicAdd(&pst[(b * 32 + chh * 16 + t) * 2],     sg[t]);
    atomicAdd(&pst[(b * 32 + chh * 16 + t) * 2 + 1], ssg[t]);
  }
  bf16* o = xt + (size_t)b * HWN * CHN + (size_t)n0 * CHN + chh * 128;
  #pragma unroll
  for (int p = 0; p < 4; p++){
    int idx = p * 256 + t;
    int n = idx >> 4, cq = idx & 15;
    int4 v = *(const int4*)(scr + n * 256 + ((cq * 16) ^ ((n & 15) << 4)));
    *(int4*)&o[(size_t)n * CHN + cq * 8] = v;
  }
}

// ---- K2: folded weights. w=0,1: wqk = {Wq,Wk}.diag(a) ; w=2: wvt[c][d] =
//          Wv[d][c].a[c] + tvb = Wv.sh+bv ; w=3 (b==0): wob = bf16(Wo) -------
__global__ __launch_bounds__(256) void wprep(const float* __restrict__ Wq,
    const float* __restrict__ Wk, const float* __restrict__ Wv,
    const float* __restrict__ Wo, const float* __restrict__ gamma,
    const float* __restrict__ beta, const float* __restrict__ bv,
    const float* __restrict__ pst, bf16* __restrict__ wqk,
    bf16* __restrict__ wvt, bf16* __restrict__ wob, float* __restrict__ tvb){
  int w = blockIdx.x, b = blockIdx.y, rt = blockIdx.z, t = threadIdx.x;
  if (w == 3 && b != 0) return;
  const float* W = (w == 0) ? Wq : ((w == 1) ? Wk : ((w == 2) ? Wv : Wo));
  __shared__ float a_s[256], sh_s[256];
  __shared__ float racc[16];
  {
    int bg = b * 32 + (t >> 3);
    float m   = pst[bg * 2] * (1.f / 131072.f);
    float var = pst[bg * 2 + 1] * (1.f / 131072.f) - m * m;
    float r = rsqrtf(var + EPSV);
    float a = r * gamma[t];
    a_s[t] = a;
    sh_s[t] = beta[t] - m * a;
  }
  if (t < 16) racc[t] = 0.f;
  __syncthreads();
  float mya = a_s[t], mysh = sh_s[t];
  int lane = t & 63;
  bf16* wo_qk = wqk + ((size_t)b << 17) + ((size_t)w << 16);
  bf16* wo_v  = wvt + ((size_t)b << 16);
  #pragma unroll
  for (int jj = 0; jj < 16; jj++){
    int j = rt * 16 + jj;
    float wv_ = W[j * 256 + t];
    if (w < 2) wo_qk[j * 256 + t] = __float2bfloat16(wv_ * mya);
    else if (w == 3) wob[j * 256 + t] = __float2bfloat16(wv_);
    else {
      wo_v[(size_t)t * 256 + j] = __float2bfloat16(wv_ * mya);  // transposed
      float p = wv_ * mysh;
      p += __shfl_xor(p, 1);  p += __shfl_xor(p, 2);  p += __shfl_xor(p, 4);
      p += __shfl_xor(p, 8);  p += __shfl_xor(p, 16); p += __shfl_xor(p, 32);
      if (lane == 0) atomicAdd(&racc[jj], p);
    }
  }
  if (w == 2){
    __syncthreads();
    if (t < 16) tvb[b * 256 + rt * 16 + t] = racc[t] + bv[rt * 16 + t];
  }
}

// ---- K3: QK projection v3: 3-buffer counted-vmcnt pipeline ------------------
__global__ __launch_bounds__(256, 2) void qk_gemm(const bf16* __restrict__ wqk,
    const bf16* __restrict__ xt, bf16* __restrict__ Eout,
    float* __restrict__ sums){
  __shared__ bf16 lW[3][256 * 32];           // 48 KB
  __shared__ bf16 lX[3][128 * 32];           // 24 KB
  int t = threadIdx.x, nt = blockIdx.x, h = blockIdx.y, b = blockIdx.z;
  const bf16* Wb = wqk + ((size_t)b << 17) + ((size_t)h << 16);
  const bf16* Xb = xt + (size_t)b * HWN * CHN + (size_t)(nt * 128) * CHN;
  int lane = t & 63, w = t >> 6, r = lane & 15, kc = lane >> 4;
  f32x4 acc[8][4] = {};                      // [i: n frag][f: wrow frag]

  auto stage = [&](int buf, int k0){
    #pragma unroll
    for (int rep = 0; rep < 4; rep++){       // W: 256 rows -> 1024 chunks
      int c = t + rep * 256; int row = c >> 2;
      int off = ((c & 3) ^ ((c >> 3) & 3)) * 8;
      gload16(Wb + (size_t)row * 256 + k0 + off, &lW[buf][c * 8]);
    }
    #pragma unroll
    for (int rep = 0; rep < 2; rep++){       // X: 128 rows -> 512 chunks
      int c = t + rep * 256; int row = c >> 2;
      int off = ((c & 3) ^ ((c >> 3) & 3)) * 8;
      gload16(Xb + (size_t)row * 256 + k0 + off, &lX[buf][c * 8]);
    }
  };

  stage(0, 0);
  stage(1, 32);
  asm volatile("s_waitcnt vmcnt(6)" ::: "memory");   // buf0 complete
  __builtin_amdgcn_s_barrier();
  int slot8 = (kc ^ ((r >> 1) & 3)) * 8;
  #pragma unroll
  for (int ks = 0; ks < 8; ks++){
    int cur = ks % 3;
    if (ks < 6) stage((ks + 2) % 3, (ks + 2) * 32);
    bf16x8 af[8], bfv[4];
    #pragma unroll
    for (int i = 0; i < 8; i++)
      af[i] = *(const bf16x8*)&lX[cur][(i * 16 + r) * 32 + slot8];
    #pragma unroll
    for (int f = 0; f < 4; f++)
      bfv[f] = *(const bf16x8*)&lW[cur][(w * 64 + f * 16 + r) * 32 + slot8];
    #pragma unroll
    for (int i = 0; i < 8; i++)
      #pragma unroll
      for (int f = 0; f < 4; f++)
        acc[i][f] = __builtin_amdgcn_mfma_f32_16x16x32_bf16(af[i], bfv[f], acc[i][f], 0, 0, 0);
    if (ks < 7){
      if (ks < 6) asm volatile("s_waitcnt vmcnt(6)" ::: "memory");  // next buf done
      else        asm volatile("s_waitcnt vmcnt(0)" ::: "memory");
      __builtin_amdgcn_s_barrier();
    }
  }

  // epilogue: 2-pass LDS transpose (scr = 32 KB over lW[0..1]).
  char* scrB = (char*)&lW[0][0];
  float colp[4] = {0.f, 0.f, 0.f, 0.f};
  int base_row = (h ? 2048 : 0) + b * 256;
  #pragma unroll
  for (int p = 0; p < 2; p++){
    __syncthreads();
    #pragma unroll
    for (int fl = 0; fl < 2; fl++){
      int f = p * 2 + fl;
      int ri = w * 32 + fl * 16 + r;         // 0..127 compacted row
      int key = (ri & 7) << 4;
      #pragma unroll
      for (int i = 0; i < 8; i++){
        s16x4 pk;
        #pragma unroll
        for (int j = 0; j < 4; j++){
          float e = __expf(acc[i][f][j]);    // |q| small: no max-sub needed
          colp[f] += e;
          pk[j] = f2s(e);
        }
        *(s16x4*)(scrB + ri * 256 + ((i * 32 + kc * 8) ^ key)) = pk;
      }
    }
    __syncthreads();
    #pragma unroll
    for (int ps = 0; ps < 8; ps++){
      int c = t + ps * 256;
      int ri = c >> 4, q = c & 15;
      int key = (ri & 7) << 4;
      int4 v = *(const int4*)(scrB + ri * 256 + ((q * 16) ^ key));
      int wrow = (ri >> 5) * 64 + (p * 2 + ((ri >> 4) & 1)) * 16 + (ri & 15);
      *(int4*)&Eout[(size_t)(base_row + wrow) * HWN + nt * 128 + q * 8] = v;
    }
  }
  #pragma unroll
  for (int f = 0; f < 4; f++){
    float v = colp[f];
    v += __shfl_xor(v, 16); v += __shfl_xor(v, 32);
    if (lane < 16)
      atomicAdd(&sums[base_row + w * 64 + f * 16 + r], v);
  }
}

// ---- K5: ES split-K. A=E_K(128 rows), B=E_Q(256) ----------------------------
__global__ __launch_bounds__(256, 2) void es_gemm(const bf16* __restrict__ Ek,
    const bf16* __restrict__ Eq, float* __restrict__ spart){
  __shared__ bf16 lA[2][128 * 32];
  __shared__ bf16 lB[2][256 * 32];
  int t = threadIdx.x, ch = blockIdx.x, mt = blockIdx.y, z = blockIdx.z;
  const bf16* At = Ek + (size_t)z * 256 * HWN + (size_t)(mt * 128) * HWN + ch * 512;
  const bf16* Bt = Eq + (size_t)z * 256 * HWN + ch * 512;
  f32x4 acc[4][8] = {};
  int lane = t & 63, w = t >> 6, r = lane & 15, kc = lane >> 4;
  int ng = w >> 1, cg = w & 1;

  auto stage = [&](int buf, int k0){
    #pragma unroll
    for (int rep = 0; rep < 2; rep++){
      int c = t + rep * 256; int row = c >> 2;
      int off = ((c & 3) ^ ((c >> 3) & 3)) * 8;
      gload16(At + (size_t)row * HWN + k0 + off, &lA[buf][c * 8]);
    }
    #pragma unroll
    for (int rep = 0; rep < 4; rep++){
      int c = t + rep * 256; int row = c >> 2;
      int off = ((c & 3) ^ ((c >> 3) & 3)) * 8;
      gload16(Bt + (size_t)row * HWN + k0 + off, &lB[buf][c * 8]);
    }
  };

  stage(0, 0);
  __syncthreads();
  int cur = 0;
  int slot8 = (kc ^ ((r >> 1) & 3)) * 8;
  for (int ks = 0; ks < 16; ks++){
    if (ks < 15) stage(cur ^ 1, (ks + 1) * 32);
    bf16x8 af[4], bfv[8];
    #pragma unroll
    for (int i = 0; i < 4; i++)
      af[i] = *(const bf16x8*)&lA[cur][(ng * 64 + i * 16 + r) * 32 + slot8];
    #pragma unroll
    for (int f = 0; f < 8; f++)
      bfv[f] = *(const bf16x8*)&lB[cur][(cg * 128 + f * 16 + r) * 32 + slot8];
    #pragma unroll
    for (int i = 0; i < 4; i++)
      #pragma unroll
      for (int f = 0; f < 8; f++)
        acc[i][f] = __builtin_amdgcn_mfma_f32_16x16x32_bf16(af[i], bfv[f], acc[i][f], 0, 0, 0);
    __syncthreads();
    cur ^= 1;
  }

  float* sp = spart + ((size_t)(z * ESCH + ch) << 16);
  #pragma unroll
  for (int f = 0; f < 8; f++){
    int q = cg * 128 + f * 16 + r;
    #pragma unroll
    for (int i = 0; i < 4; i++){
      int k0i = mt * 128 + ng * 64 + i * 16 + kc * 4;
      *(f32x4*)&sp[q * 256 + k0i] = acc[i][f];
    }
  }
}

// ---- K6a: reduce split-K partials of ES (float4) ----------------------------
__global__ void reduce_S(const float* __restrict__ sp, float* __restrict__ S){
  size_t i = ((size_t)blockIdx.x * 256 + threadIdx.x) * 4;   // 8*65536 elems
  size_t b = i >> 16, cd = i & 65535;
  float4 s = {0.f, 0.f, 0.f, 0.f};
  #pragma unroll
  for (int ch = 0; ch < ESCH; ch++){
    float4 v = *(const float4*)&sp[((b * ESCH + ch) << 16) + cd];
    s.x += v.x; s.y += v.y; s.z += v.z; s.w += v.w;
  }
  *(float4*)&S[i] = s;
}

// ---- K6b: T1t[d][c] = S[c][d] / (16 sq[c] sk[d]) -> bf16 (LDS transpose) ----
__global__ __launch_bounds__(256) void scaleS_t(const float* __restrict__ S,
    const float* __restrict__ sums, bf16* __restrict__ T1t){
  int id = blockIdx.x, b = blockIdx.y;
  int dt = id >> 2, ct = id & 3, t = threadIdx.x;
  __shared__ float tile[64][65];
  __shared__ float sq_s[64], sk_s[64];
  if (t < 64)       sq_s[t]      = 0.0625f / sums[b * 256 + ct * 64 + t];
  else if (t < 128) sk_s[t - 64] = 1.f / sums[2048 + b * 256 + dt * 64 + (t - 64)];
  const float* Sb = S + ((size_t)b << 16);
  #pragma unroll
  for (int i = 0; i < 4; i++){
    int c_l = i * 16 + (t >> 4);
    int d_l0 = (t & 15) * 4;
    float4 v = *(const float4*)&Sb[(size_t)(ct * 64 + c_l) * 256 + dt * 64 + d_l0];
    tile[d_l0 + 0][c_l] = v.x;
    tile[d_l0 + 1][c_l] = v.y;
    tile[d_l0 + 2][c_l] = v.z;
    tile[d_l0 + 3][c_l] = v.w;
  }
  __syncthreads();
  bf16* Tb = T1t + ((size_t)b << 16);
  #pragma unroll
  for (int i = 0; i < 4; i++){
    int d_l = i * 16 + (t >> 4);
    int c_l0 = (t & 15) * 4;
    s16x4 pk;
    #pragma unroll
    for (int jj = 0; jj < 4; jj++)
      pk[jj] = f2s(tile[d_l][c_l0 + jj] * sq_s[c_l0 + jj] * sk_s[d_l]);
    *(s16x4*)&Tb[(size_t)(dt * 64 + d_l) * 256 + ct * 64 + c_l0] = pk;
  }
}

// ---- K6c: tiny NT MFMA GEMM: out[bcol][arow] = sum_k A[arow][k].B[bcol][k] --
__global__ __launch_bounds__(256, 2) void nt_gemm(const bf16* __restrict__ A,
    const bf16* __restrict__ B, bf16* __restrict__ out,
    long Asb, long Bsb, long Osb){
  __shared__ bf16 lA[2][256 * 32];
  __shared__ bf16 lB[2][128 * 32];
  int t = threadIdx.x, mt = blockIdx.x, b = blockIdx.y;
  const bf16* Ab = A + (size_t)b * Asb;
  const bf16* Bb = B + (size_t)b * Bsb + (size_t)(mt * 128) * 256;
  bf16* Ob = out + (size_t)b * Osb + (size_t)(mt * 128) * 256;
  int lane = t & 63, w = t >> 6, r = lane & 15, kc = lane >> 4;
  f32x4 acc[16][2] = {};

  auto stage = [&](int buf, int k0){
    #pragma unroll
    for (int rep = 0; rep < 4; rep++){           // 1024 chunks: full 256 rows
      int c = t + rep * 256; int row = c >> 2, off = (c & 3) * 8;
      gload16(Ab + (size_t)row * 256 + k0 + off, &lA[buf][c * 8]);
    }
    #pragma unroll
    for (int rep = 0; rep < 2; rep++){           // 512 chunks: full 128 rows
      int c = t + rep * 256; int row = c >> 2, off = (c & 3) * 8;
      gload16(Bb + (size_t)row * 256 + k0 + off, &lB[buf][c * 8]);
    }
  };

  stage(0, 0);
  __syncthreads();
  int cur = 0;
  for (int ks = 0; ks < 8; ks++){
    if (ks < 7) stage(cur ^ 1, (ks + 1) * 32);
    bf16x8 bfv[2];
    #pragma unroll
    for (int f = 0; f < 2; f++)
      bfv[f] = *(const bf16x8*)&lB[cur][(w * 32 + f * 16 + r) * 32 + kc * 8];
    #pragma unroll
    for (int i = 0; i < 16; i++){
      bf16x8 af = *(const bf16x8*)&lA[cur][(i * 16 + r) * 32 + kc * 8];
      acc[i][0] = __builtin_amdgcn_mfma_f32_16x16x32_bf16(af, bfv[0], acc[i][0], 0, 0, 0);
      acc[i][1] = __builtin_amdgcn_mfma_f32_16x16x32_bf16(af, bfv[1], acc[i][1], 0, 0, 0);
    }
    __syncthreads();
    cur ^= 1;
  }

  #pragma unroll
  for (int f = 0; f < 2; f++){
    int bcol = w * 32 + f * 16 + r;
    #pragma unroll
    for (int i = 0; i < 16; i++){
      s16x4 pk;
      #pragma unroll
      for (int j = 0; j < 4; j++) pk[j] = f2s(acc[i][f][j]);
      *(s16x4*)&Ob[(size_t)bcol * 256 + i * 16 + kc * 4] = pk;
    }
  }
}

// ---- K6d: beff[o] = M[o,:].tvb + bo ------------------------------------------
__global__ __launch_bounds__(256) void beff_k(const bf16* __restrict__ Mbf,
    const float* __restrict__ tvb, const float* __restrict__ bo,
    float* __restrict__ beff){
  int b = blockIdx.x, t = threadIdx.x;
  __shared__ float tv[256];
  tv[t] = tvb[b * 256 + t];
  __syncthreads();
  const bf16* Mr = Mbf + ((size_t)b << 16) + (size_t)t * 256;
  float s = 0.f;
  #pragma unroll
  for (int k = 0; k < 32; k++){
    bf16x8 v = *(const bf16x8*)&Mr[k * 8];
    #pragma unroll
    for (int e = 0; e < 8; e++) s += s2f(v[e]) * tv[k * 8 + e];
  }
  beff[b * 256 + t] = s + bo[t];
}

// ---- K7: out[o][n] = N . x^T + b_eff. A=xt(128 n), B=N(256 o) ---------------
__global__ __launch_bounds__(256, 2) void out_gemm(const bf16* __restrict__ xt,
    const bf16* __restrict__ Nb, const float* __restrict__ beff,
    float* __restrict__ out){
  __shared__ bf16 lA[2][128 * 32];
  __shared__ bf16 lB[2][256 * 32];
  int t = threadIdx.x, nt = blockIdx.x, z = blockIdx.y;
  const bf16* At = xt + (size_t)z * HWN * CHN + (size_t)(nt * 128) * CHN;
  const bf16* Bt = Nb + (size_t)z * 65536;
  f32x4 acc[4][8] = {};
  int lane = t & 63, w = t >> 6, r = lane & 15, kc = lane >> 4;
  int ng = w >> 1, cg = w & 1;

  auto stage = [&](int buf, int k0){
    #pragma unroll
    for (int rep = 0; rep < 2; rep++){
      int c = t + rep * 256; int row = c >> 2;
      int off = ((c & 3) ^ ((c >> 3) & 3)) * 8;
      gload16(At + (size_t)row * 256 + k0 + off, &lA[buf][c * 8]);
    }
    #pragma unroll
    for (int rep = 0; rep < 4; rep++){
      int c = t + rep * 256; int row = c >> 2;
      int off = ((c & 3) ^ ((c >> 3) & 3)) * 8;
      gload16(Bt + (size_t)row * 256 + k0 + off, &lB[buf][c * 8]);
    }
  };

  stage(0, 0);
  __syncthreads();
  int cur = 0;
  int slot8 = (kc ^ ((r >> 1) & 3)) * 8;
  for (int ks = 0; ks < 8; ks++){
    if (ks < 7) stage(cur ^ 1, (ks + 1) * 32);
    bf16x8 af[4], bfv[8];
    #pragma unroll
    for (int i = 0; i < 4; i++)
      af[i] = *(const bf16x8*)&lA[cur][(ng * 64 + i * 16 + r) * 32 + slot8];
    #pragma unroll
    for (int f = 0; f < 8; f++)
      bfv[f] = *(const bf16x8*)&lB[cur][(cg * 128 + f * 16 + r) * 32 + slot8];
    #pragma unroll
    for (int i = 0; i < 4; i++)
      #pragma unroll
      for (int f = 0; f < 8; f++)
        acc[i][f] = __builtin_amdgcn_mfma_f32_16x16x32_bf16(af[i], bfv[f], acc[i][f], 0, 0, 0);
    __syncthreads();
    cur ^= 1;
  }

  float* ob = out + (size_t)z * CHN * HWN;
  #pragma unroll
  for (int f = 0; f < 8; f++){
    int o = cg * 128 + f * 16 + r;
    float bb = beff[z * 256 + o];
    #pragma unroll
    for (int i = 0; i < 4; i++){
      int n0 = nt * 128 + ng * 64 + i * 16 + kc * 4;
      float4 st = { acc[i][f][0] + bb, acc[i][f][1] + bb,
                    acc[i][f][2] + bb, acc[i][f][3] + bb };
      *(float4*)&ob[(size_t)o * HWN + n0] = st;
    }
  }
}

// ------------------------------------------------------------------------------
extern "C" void kernel_launch(void* const* d_in, const int* in_sizes, int n_in,
                              void* d_out, int out_size, void* d_ws, size_t ws_size,
                              hipStream_t stream){
  const float* x     = (const float*)d_in[0];
  const float* gamma = (const float*)d_in[1];
  const float* beta  = (const float*)d_in[2];
  const float* Wq    = (const float*)d_in[3];
  const float* Wk    = (const float*)d_in[5];
  const float* Wv    = (const float*)d_in[7];
  const float* bv    = (const float*)d_in[8];
  const float* Wo    = (const float*)d_in[9];
  const float* bo    = (const float*)d_in[10];
  // bq/bk and GN-shift are per-row constants in Q/K -> cancel in softmax.
  // V path folded: out = N.x + b_eff; N = Wo.diag(1/16sq).S.diag(1/sk).Wv.diag(a)

  char* ws = (char*)d_ws;
  bf16*  xt    = (bf16*) (ws + 0);            // 64 MiB x^T bf16 [b][n][c]
  float* spart = (float*)(ws + 67108864);     // 64 MiB ES split-K partials
  bf16*  wqk   = (bf16*) (ws + 134217728);    // 2 MiB  W'qk [b][512][256]
  bf16*  wob   = (bf16*) (ws + 136314880);    // 128 KiB Wo bf16
  bf16*  wvt   = (bf16*) (ws + 136445952);    // 1 MiB  Wv'^T [b][c][d]
  float* S     = (float*)(ws + 137494528);    // 2 MiB  ES [b][c][d]
  bf16*  T1t   = (bf16*) (ws + 139591680);    // 1 MiB  scaled S^T [b][d][c]
  bf16*  Mbf   = (bf16*) (ws + 140640256);    // 1 MiB  M bf16 [b][o][d]
  bf16*  Nb    = (bf16*) (ws + 141688832);    // 1 MiB  N bf16 [b][o][c]
  float* sums  = (float*)(ws + 142737408);    // 16 KiB sq[2048], sk[2048]
  float* pst   = (float*)(ws + 142753792);    // 2 KiB  GN partial s/ss
  float* tvb   = (float*)(ws + 142755840);    // 8 KiB  Wv.sh + bv per batch
  float* beff  = (float*)(ws + 142764032);    // 8 KiB  effective out bias

  bf16* Qb = (bf16*)d_out;                    // E_Q rows 0..2047
  bf16* Kb = Qb + (size_t)2048 * HWN;         // E_K rows 2048..4095

  hipMemsetAsync(sums, 0, 4096 * sizeof(float), stream);
  hipMemsetAsync(pst,  0,  512 * sizeof(float), stream);

  xstats_t<<<dim3(256, 2, 8), dim3(256), 0, stream>>>(x, xt, pst);
  wprep<<<dim3(4, 8, 16), dim3(256), 0, stream>>>(Wq, Wk, Wv, Wo, gamma, beta,
                                                  bv, pst, wqk, wvt, wob, tvb);
  qk_gemm<<<dim3(128, 2, 8), dim3(256), 0, stream>>>(wqk, xt, Qb, sums);
  es_gemm<<<dim3(ESCH, 2, 8), dim3(256), 0, stream>>>(Kb, Qb, spart);
  reduce_S<<<dim3(512), dim3(256), 0, stream>>>(spart, S);
  scaleS_t<<<dim3(16, 8), dim3(256), 0, stream>>>(S, sums, T1t);
  // M[o][d] = sum_c Wo[o][c] . T1t[d][c]
  nt_gemm<<<dim3(2, 8), dim3(256), 0, stream>>>(T1t, wob, Mbf, 65536L, 0L, 65536L);
  beff_k<<<dim3(8), dim3(256), 0, stream>>>(Mbf, tvb, bo, beff);
  // N[o][c] = sum_d wvt[c][d] . M[o][d]
  nt_gemm<<<dim3(2, 8), dim3(256), 0, stream>>>(wvt, Mbf, Nb, 65536L, 65536L, 65536L);
  out_gemm<<<dim3(128, 8), dim3(256), 0, stream>>>(xt, Nb, beff, (float*)d_out);
}

// Round 18
// 281.188 us; speedup vs baseline: 1.0175x; 1.0175x over previous
//
#include <hip/hip_runtime.h>
#include <hip/hip_bf16.h>

#define BATCH 8
#define CHN 256
#define HWN 16384
#define EPSV 1e-6f
#define ESCH 32

typedef __attribute__((ext_vector_type(8))) short bf16x8;
typedef __attribute__((ext_vector_type(4))) short s16x4;
typedef __attribute__((ext_vector_type(4))) float f32x4;
typedef __hip_bfloat16 bf16;

__device__ __forceinline__ short f2s(float f){
  union { bf16 h; short s; } u; u.h = __float2bfloat16(f); return u.s;
}
__device__ __forceinline__ float s2f(short s){
  union { unsigned u; float f; } v; v.u = ((unsigned)(unsigned short)s) << 16; return v.f;
}
__device__ __forceinline__ void gload16(const bf16* g, bf16* l){
  __builtin_amdgcn_global_load_lds((const __attribute__((address_space(1))) void*)g,
                                   (__attribute__((address_space(3))) void*)l, 16, 0, 0);
}

// ---- K1 v8: read x once: GN stats + transpose x^T -> bf16 -------------------
// Half-c blocks [128 c][64 n], 16.5 KB LDS -> 8 blocks/CU. Swizzle key
// ((row>>2)&15)<<4: 16 distinct keys per wave-instruction (row>>2 == t&15).
__global__ __launch_bounds__(256) void xstats_t(const float* __restrict__ x,
    bf16* __restrict__ xt, float* __restrict__ pst){
  int b = blockIdx.z, chh = blockIdx.y, n0 = blockIdx.x * 64;
  __shared__ char scr[64 * 256];              // [n][c' bf16], 16 KB swizzled
  __shared__ float sg[16], ssg[16];
  int t = threadIdx.x, lane = t & 63, w = t >> 6;
  if (t < 16){ sg[t] = 0.f; ssg[t] = 0.f; }
  __syncthreads();
  const float* xb = x + (size_t)b * CHN * HWN + (size_t)(chh * 128) * HWN
                    + n0 + (t & 15) * 4;
  int c0 = t >> 4;                            // 0..15
  #pragma unroll
  for (int i = 0; i < 8; i++){
    int cl = i * 16 + c0;                     // 0..127 local c
    float4 v = *(const float4*)(xb + (size_t)cl * HWN);
    int nf = (t & 15) * 4;
    #pragma unroll
    for (int j = 0; j < 4; j++){
      int row = nf + j;
      float e = j == 0 ? v.x : (j == 1 ? v.y : (j == 2 ? v.z : v.w));
      int key = ((row >> 2) & 15) << 4;
      *(short*)(scr + row * 256 + ((cl * 2) ^ key)) = f2s(e);
    }
    float s  = v.x + v.y + v.z + v.w;
    float ss = v.x*v.x + v.y*v.y + v.z*v.z + v.w*v.w;
    s  += __shfl_xor(s, 1);  s  += __shfl_xor(s, 2);  s  += __shfl_xor(s, 4);
    s  += __shfl_xor(s, 8);  s  += __shfl_xor(s, 16); s  += __shfl_xor(s, 32);
    ss += __shfl_xor(ss, 1); ss += __shfl_xor(ss, 2); ss += __shfl_xor(ss, 4);
    ss += __shfl_xor(ss, 8); ss += __shfl_xor(ss, 16); ss += __shfl_xor(ss, 32);
    if (lane == 0){                           // wave's 4 cl all in group i*2+(w>>1)
      atomicAdd(&sg[i * 2 + (w >> 1)], s);
      atomicAdd(&ssg[i * 2 + (w >> 1)], ss);
    }
  }
  __syncthreads();
  if (t < 16){
    atomicAdd(&pst[(b * 32 + chh * 16 + t) * 2],     sg[t]);
    atomicAdd(&pst[(b * 32 + chh * 16 + t) * 2 + 1], ssg[t]);
  }
  bf16* o = xt + (size_t)b * HWN * CHN + (size_t)n0 * CHN + chh * 128;
  #pragma unroll
  for (int p = 0; p < 4; p++){
    int idx = p * 256 + t;
    int n = idx >> 4, cq = idx & 15;
    int key = ((n >> 2) & 15) << 4;
    int4 v = *(const int4*)(scr + n * 256 + ((cq * 16) ^ key));
    *(int4*)&o[(size_t)n * CHN + cq * 8] = v;
  }
}

// ---- K2: folded weights. w=0,1: wqk = {Wq,Wk}.diag(a) ; w=2: wvt[c][d] =
//          Wv[d][c].a[c] + tvb = Wv.sh+bv ; w=3 (b==0): wob = bf16(Wo) -------
__global__ __launch_bounds__(256) void wprep(const float* __restrict__ Wq,
    const float* __restrict__ Wk, const float* __restrict__ Wv,
    const float* __restrict__ Wo, const float* __restrict__ gamma,
    const float* __restrict__ beta, const float* __restrict__ bv,
    const float* __restrict__ pst, bf16* __restrict__ wqk,
    bf16* __restrict__ wvt, bf16* __restrict__ wob, float* __restrict__ tvb){
  int w = blockIdx.x, b = blockIdx.y, rt = blockIdx.z, t = threadIdx.x;
  if (w == 3 && b != 0) return;
  const float* W = (w == 0) ? Wq : ((w == 1) ? Wk : ((w == 2) ? Wv : Wo));
  __shared__ float a_s[256], sh_s[256];
  __shared__ float racc[16];
  {
    int bg = b * 32 + (t >> 3);
    float m   = pst[bg * 2] * (1.f / 131072.f);
    float var = pst[bg * 2 + 1] * (1.f / 131072.f) - m * m;
    float r = rsqrtf(var + EPSV);
    float a = r * gamma[t];
    a_s[t] = a;
    sh_s[t] = beta[t] - m * a;
  }
  if (t < 16) racc[t] = 0.f;
  __syncthreads();
  float mya = a_s[t], mysh = sh_s[t];
  int lane = t & 63;
  bf16* wo_qk = wqk + ((size_t)b << 17) + ((size_t)w << 16);
  bf16* wo_v  = wvt + ((size_t)b << 16);
  #pragma unroll
  for (int jj = 0; jj < 16; jj++){
    int j = rt * 16 + jj;
    float wv_ = W[j * 256 + t];
    if (w < 2) wo_qk[j * 256 + t] = __float2bfloat16(wv_ * mya);
    else if (w == 3) wob[j * 256 + t] = __float2bfloat16(wv_);
    else {
      wo_v[(size_t)t * 256 + j] = __float2bfloat16(wv_ * mya);  // transposed
      float p = wv_ * mysh;
      p += __shfl_xor(p, 1);  p += __shfl_xor(p, 2);  p += __shfl_xor(p, 4);
      p += __shfl_xor(p, 8);  p += __shfl_xor(p, 16); p += __shfl_xor(p, 32);
      if (lane == 0) atomicAdd(&racc[jj], p);
    }
  }
  if (w == 2){
    __syncthreads();
    if (t < 16) tvb[b * 256 + rt * 16 + t] = racc[t] + bv[rt * 16 + t];
  }
}

// ---- K3: QK projection v3: 3-buffer counted-vmcnt pipeline ------------------
__global__ __launch_bounds__(256, 2) void qk_gemm(const bf16* __restrict__ wqk,
    const bf16* __restrict__ xt, bf16* __restrict__ Eout,
    float* __restrict__ sums){
  __shared__ bf16 lW[3][256 * 32];           // 48 KB
  __shared__ bf16 lX[3][128 * 32];           // 24 KB
  int t = threadIdx.x, nt = blockIdx.x, h = blockIdx.y, b = blockIdx.z;
  const bf16* Wb = wqk + ((size_t)b << 17) + ((size_t)h << 16);
  const bf16* Xb = xt + (size_t)b * HWN * CHN + (size_t)(nt * 128) * CHN;
  int lane = t & 63, w = t >> 6, r = lane & 15, kc = lane >> 4;
  f32x4 acc[8][4] = {};                      // [i: n frag][f: wrow frag]

  auto stage = [&](int buf, int k0){
    #pragma unroll
    for (int rep = 0; rep < 4; rep++){       // W: 256 rows -> 1024 chunks
      int c = t + rep * 256; int row = c >> 2;
      int off = ((c & 3) ^ ((c >> 3) & 3)) * 8;
      gload16(Wb + (size_t)row * 256 + k0 + off, &lW[buf][c * 8]);
    }
    #pragma unroll
    for (int rep = 0; rep < 2; rep++){       // X: 128 rows -> 512 chunks
      int c = t + rep * 256; int row = c >> 2;
      int off = ((c & 3) ^ ((c >> 3) & 3)) * 8;
      gload16(Xb + (size_t)row * 256 + k0 + off, &lX[buf][c * 8]);
    }
  };

  stage(0, 0);
  stage(1, 32);
  asm volatile("s_waitcnt vmcnt(6)" ::: "memory");   // buf0 complete
  __builtin_amdgcn_s_barrier();
  int slot8 = (kc ^ ((r >> 1) & 3)) * 8;
  #pragma unroll
  for (int ks = 0; ks < 8; ks++){
    int cur = ks % 3;
    if (ks < 6) stage((ks + 2) % 3, (ks + 2) * 32);
    bf16x8 af[8], bfv[4];
    #pragma unroll
    for (int i = 0; i < 8; i++)
      af[i] = *(const bf16x8*)&lX[cur][(i * 16 + r) * 32 + slot8];
    #pragma unroll
    for (int f = 0; f < 4; f++)
      bfv[f] = *(const bf16x8*)&lW[cur][(w * 64 + f * 16 + r) * 32 + slot8];
    #pragma unroll
    for (int i = 0; i < 8; i++)
      #pragma unroll
      for (int f = 0; f < 4; f++)
        acc[i][f] = __builtin_amdgcn_mfma_f32_16x16x32_bf16(af[i], bfv[f], acc[i][f], 0, 0, 0);
    if (ks < 7){
      if (ks < 6) asm volatile("s_waitcnt vmcnt(6)" ::: "memory");  // next buf done
      else        asm volatile("s_waitcnt vmcnt(0)" ::: "memory");
      __builtin_amdgcn_s_barrier();
    }
  }

  // epilogue: 2-pass LDS transpose (scr = 32 KB over lW[0..1]).
  char* scrB = (char*)&lW[0][0];
  float colp[4] = {0.f, 0.f, 0.f, 0.f};
  int base_row = (h ? 2048 : 0) + b * 256;
  #pragma unroll
  for (int p = 0; p < 2; p++){
    __syncthreads();
    #pragma unroll
    for (int fl = 0; fl < 2; fl++){
      int f = p * 2 + fl;
      int ri = w * 32 + fl * 16 + r;         // 0..127 compacted row
      int key = (ri & 7) << 4;
      #pragma unroll
      for (int i = 0; i < 8; i++){
        s16x4 pk;
        #pragma unroll
        for (int j = 0; j < 4; j++){
          float e = __expf(acc[i][f][j]);    // |q| small: no max-sub needed
          colp[f] += e;
          pk[j] = f2s(e);
        }
        *(s16x4*)(scrB + ri * 256 + ((i * 32 + kc * 8) ^ key)) = pk;
      }
    }
    __syncthreads();
    #pragma unroll
    for (int ps = 0; ps < 8; ps++){
      int c = t + ps * 256;
      int ri = c >> 4, q = c & 15;
      int key = (ri & 7) << 4;
      int4 v = *(const int4*)(scrB + ri * 256 + ((q * 16) ^ key));
      int wrow = (ri >> 5) * 64 + (p * 2 + ((ri >> 4) & 1)) * 16 + (ri & 15);
      *(int4*)&Eout[(size_t)(base_row + wrow) * HWN + nt * 128 + q * 8] = v;
    }
  }
  #pragma unroll
  for (int f = 0; f < 4; f++){
    float v = colp[f];
    v += __shfl_xor(v, 16); v += __shfl_xor(v, 32);
    if (lane < 16)
      atomicAdd(&sums[base_row + w * 64 + f * 16 + r], v);
  }
}

// ---- K5: ES split-K. A=E_K(128 rows), B=E_Q(256) ----------------------------
__global__ __launch_bounds__(256, 2) void es_gemm(const bf16* __restrict__ Ek,
    const bf16* __restrict__ Eq, float* __restrict__ spart){
  __shared__ bf16 lA[2][128 * 32];
  __shared__ bf16 lB[2][256 * 32];
  int t = threadIdx.x, ch = blockIdx.x, mt = blockIdx.y, z = blockIdx.z;
  const bf16* At = Ek + (size_t)z * 256 * HWN + (size_t)(mt * 128) * HWN + ch * 512;
  const bf16* Bt = Eq + (size_t)z * 256 * HWN + ch * 512;
  f32x4 acc[4][8] = {};
  int lane = t & 63, w = t >> 6, r = lane & 15, kc = lane >> 4;
  int ng = w >> 1, cg = w & 1;

  auto stage = [&](int buf, int k0){
    #pragma unroll
    for (int rep = 0; rep < 2; rep++){
      int c = t + rep * 256; int row = c >> 2;
      int off = ((c & 3) ^ ((c >> 3) & 3)) * 8;
      gload16(At + (size_t)row * HWN + k0 + off, &lA[buf][c * 8]);
    }
    #pragma unroll
    for (int rep = 0; rep < 4; rep++){
      int c = t + rep * 256; int row = c >> 2;
      int off = ((c & 3) ^ ((c >> 3) & 3)) * 8;
      gload16(Bt + (size_t)row * HWN + k0 + off, &lB[buf][c * 8]);
    }
  };

  stage(0, 0);
  __syncthreads();
  int cur = 0;
  int slot8 = (kc ^ ((r >> 1) & 3)) * 8;
  for (int ks = 0; ks < 16; ks++){
    if (ks < 15) stage(cur ^ 1, (ks + 1) * 32);
    bf16x8 af[4], bfv[8];
    #pragma unroll
    for (int i = 0; i < 4; i++)
      af[i] = *(const bf16x8*)&lA[cur][(ng * 64 + i * 16 + r) * 32 + slot8];
    #pragma unroll
    for (int f = 0; f < 8; f++)
      bfv[f] = *(const bf16x8*)&lB[cur][(cg * 128 + f * 16 + r) * 32 + slot8];
    #pragma unroll
    for (int i = 0; i < 4; i++)
      #pragma unroll
      for (int f = 0; f < 8; f++)
        acc[i][f] = __builtin_amdgcn_mfma_f32_16x16x32_bf16(af[i], bfv[f], acc[i][f], 0, 0, 0);
    __syncthreads();
    cur ^= 1;
  }

  float* sp = spart + ((size_t)(z * ESCH + ch) << 16);
  #pragma unroll
  for (int f = 0; f < 8; f++){
    int q = cg * 128 + f * 16 + r;
    #pragma unroll
    for (int i = 0; i < 4; i++){
      int k0i = mt * 128 + ng * 64 + i * 16 + kc * 4;
      *(f32x4*)&sp[q * 256 + k0i] = acc[i][f];
    }
  }
}

// ---- K6a: reduce split-K partials of ES (float4) ----------------------------
__global__ void reduce_S(const float* __restrict__ sp, float* __restrict__ S){
  size_t i = ((size_t)blockIdx.x * 256 + threadIdx.x) * 4;   // 8*65536 elems
  size_t b = i >> 16, cd = i & 65535;
  float4 s = {0.f, 0.f, 0.f, 0.f};
  #pragma unroll
  for (int ch = 0; ch < ESCH; ch++){
    float4 v = *(const float4*)&sp[((b * ESCH + ch) << 16) + cd];
    s.x += v.x; s.y += v.y; s.z += v.z; s.w += v.w;
  }
  *(float4*)&S[i] = s;
}

// ---- K6b: T1t[d][c] = S[c][d] / (16 sq[c] sk[d]) -> bf16 (LDS transpose) ----
__global__ __launch_bounds__(256) void scaleS_t(const float* __restrict__ S,
    const float* __restrict__ sums, bf16* __restrict__ T1t){
  int id = blockIdx.x, b = blockIdx.y;
  int dt = id >> 2, ct = id & 3, t = threadIdx.x;
  __shared__ float tile[64][65];
  __shared__ float sq_s[64], sk_s[64];
  if (t < 64)       sq_s[t]      = 0.0625f / sums[b * 256 + ct * 64 + t];
  else if (t < 128) sk_s[t - 64] = 1.f / sums[2048 + b * 256 + dt * 64 + (t - 64)];
  const float* Sb = S + ((size_t)b << 16);
  #pragma unroll
  for (int i = 0; i < 4; i++){
    int c_l = i * 16 + (t >> 4);
    int d_l0 = (t & 15) * 4;
    float4 v = *(const float4*)&Sb[(size_t)(ct * 64 + c_l) * 256 + dt * 64 + d_l0];
    tile[d_l0 + 0][c_l] = v.x;
    tile[d_l0 + 1][c_l] = v.y;
    tile[d_l0 + 2][c_l] = v.z;
    tile[d_l0 + 3][c_l] = v.w;
  }
  __syncthreads();
  bf16* Tb = T1t + ((size_t)b << 16);
  #pragma unroll
  for (int i = 0; i < 4; i++){
    int d_l = i * 16 + (t >> 4);
    int c_l0 = (t & 15) * 4;
    s16x4 pk;
    #pragma unroll
    for (int jj = 0; jj < 4; jj++)
      pk[jj] = f2s(tile[d_l][c_l0 + jj] * sq_s[c_l0 + jj] * sk_s[d_l]);
    *(s16x4*)&Tb[(size_t)(dt * 64 + d_l) * 256 + ct * 64 + c_l0] = pk;
  }
}

// ---- K6c: tiny NT MFMA GEMM: out[bcol][arow] = sum_k A[arow][k].B[bcol][k] --
__global__ __launch_bounds__(256, 2) void nt_gemm(const bf16* __restrict__ A,
    const bf16* __restrict__ B, bf16* __restrict__ out,
    long Asb, long Bsb, long Osb){
  __shared__ bf16 lA[2][256 * 32];
  __shared__ bf16 lB[2][128 * 32];
  int t = threadIdx.x, mt = blockIdx.x, b = blockIdx.y;
  const bf16* Ab = A + (size_t)b * Asb;
  const bf16* Bb = B + (size_t)b * Bsb + (size_t)(mt * 128) * 256;
  bf16* Ob = out + (size_t)b * Osb + (size_t)(mt * 128) * 256;
  int lane = t & 63, w = t >> 6, r = lane & 15, kc = lane >> 4;
  f32x4 acc[16][2] = {};

  auto stage = [&](int buf, int k0){
    #pragma unroll
    for (int rep = 0; rep < 4; rep++){           // 1024 chunks: full 256 rows
      int c = t + rep * 256; int row = c >> 2, off = (c & 3) * 8;
      gload16(Ab + (size_t)row * 256 + k0 + off, &lA[buf][c * 8]);
    }
    #pragma unroll
    for (int rep = 0; rep < 2; rep++){           // 512 chunks: full 128 rows
      int c = t + rep * 256; int row = c >> 2, off = (c & 3) * 8;
      gload16(Bb + (size_t)row * 256 + k0 + off, &lB[buf][c * 8]);
    }
  };

  stage(0, 0);
  __syncthreads();
  int cur = 0;
  for (int ks = 0; ks < 8; ks++){
    if (ks < 7) stage(cur ^ 1, (ks + 1) * 32);
    bf16x8 bfv[2];
    #pragma unroll
    for (int f = 0; f < 2; f++)
      bfv[f] = *(const bf16x8*)&lB[cur][(w * 32 + f * 16 + r) * 32 + kc * 8];
    #pragma unroll
    for (int i = 0; i < 16; i++){
      bf16x8 af = *(const bf16x8*)&lA[cur][(i * 16 + r) * 32 + kc * 8];
      acc[i][0] = __builtin_amdgcn_mfma_f32_16x16x32_bf16(af, bfv[0], acc[i][0], 0, 0, 0);
      acc[i][1] = __builtin_amdgcn_mfma_f32_16x16x32_bf16(af, bfv[1], acc[i][1], 0, 0, 0);
    }
    __syncthreads();
    cur ^= 1;
  }

  #pragma unroll
  for (int f = 0; f < 2; f++){
    int bcol = w * 32 + f * 16 + r;
    #pragma unroll
    for (int i = 0; i < 16; i++){
      s16x4 pk;
      #pragma unroll
      for (int j = 0; j < 4; j++) pk[j] = f2s(acc[i][f][j]);
      *(s16x4*)&Ob[(size_t)bcol * 256 + i * 16 + kc * 4] = pk;
    }
  }
}

// ---- K6d: beff[o] = M[o,:].tvb + bo ------------------------------------------
__global__ __launch_bounds__(256) void beff_k(const bf16* __restrict__ Mbf,
    const float* __restrict__ tvb, const float* __restrict__ bo,
    float* __restrict__ beff){
  int b = blockIdx.x, t = threadIdx.x;
  __shared__ float tv[256];
  tv[t] = tvb[b * 256 + t];
  __syncthreads();
  const bf16* Mr = Mbf + ((size_t)b << 16) + (size_t)t * 256;
  float s = 0.f;
  #pragma unroll
  for (int k = 0; k < 32; k++){
    bf16x8 v = *(const bf16x8*)&Mr[k * 8];
    #pragma unroll
    for (int e = 0; e < 8; e++) s += s2f(v[e]) * tv[k * 8 + e];
  }
  beff[b * 256 + t] = s + bo[t];
}

// ---- K7: out[o][n] = N . x^T + b_eff. A=xt(128 n), B=N(256 o) ---------------
__global__ __launch_bounds__(256, 2) void out_gemm(const bf16* __restrict__ xt,
    const bf16* __restrict__ Nb, const float* __restrict__ beff,
    float* __restrict__ out){
  __shared__ bf16 lA[2][128 * 32];
  __shared__ bf16 lB[2][256 * 32];
  int t = threadIdx.x, nt = blockIdx.x, z = blockIdx.y;
  const bf16* At = xt + (size_t)z * HWN * CHN + (size_t)(nt * 128) * CHN;
  const bf16* Bt = Nb + (size_t)z * 65536;
  f32x4 acc[4][8] = {};
  int lane = t & 63, w = t >> 6, r = lane & 15, kc = lane >> 4;
  int ng = w >> 1, cg = w & 1;

  auto stage = [&](int buf, int k0){
    #pragma unroll
    for (int rep = 0; rep < 2; rep++){
      int c = t + rep * 256; int row = c >> 2;
      int off = ((c & 3) ^ ((c >> 3) & 3)) * 8;
      gload16(At + (size_t)row * 256 + k0 + off, &lA[buf][c * 8]);
    }
    #pragma unroll
    for (int rep = 0; rep < 4; rep++){
      int c = t + rep * 256; int row = c >> 2;
      int off = ((c & 3) ^ ((c >> 3) & 3)) * 8;
      gload16(Bt + (size_t)row * 256 + k0 + off, &lB[buf][c * 8]);
    }
  };

  stage(0, 0);
  __syncthreads();
  int cur = 0;
  int slot8 = (kc ^ ((r >> 1) & 3)) * 8;
  for (int ks = 0; ks < 8; ks++){
    if (ks < 7) stage(cur ^ 1, (ks + 1) * 32);
    bf16x8 af[4], bfv[8];
    #pragma unroll
    for (int i = 0; i < 4; i++)
      af[i] = *(const bf16x8*)&lA[cur][(ng * 64 + i * 16 + r) * 32 + slot8];
    #pragma unroll
    for (int f = 0; f < 8; f++)
      bfv[f] = *(const bf16x8*)&lB[cur][(cg * 128 + f * 16 + r) * 32 + slot8];
    #pragma unroll
    for (int i = 0; i < 4; i++)
      #pragma unroll
      for (int f = 0; f < 8; f++)
        acc[i][f] = __builtin_amdgcn_mfma_f32_16x16x32_bf16(af[i], bfv[f], acc[i][f], 0, 0, 0);
    __syncthreads();
    cur ^= 1;
  }

  float* ob = out + (size_t)z * CHN * HWN;
  #pragma unroll
  for (int f = 0; f < 8; f++){
    int o = cg * 128 + f * 16 + r;
    float bb = beff[z * 256 + o];
    #pragma unroll
    for (int i = 0; i < 4; i++){
      int n0 = nt * 128 + ng * 64 + i * 16 + kc * 4;
      float4 st = { acc[i][f][0] + bb, acc[i][f][1] + bb,
                    acc[i][f][2] + bb, acc[i][f][3] + bb };
      *(float4*)&ob[(size_t)o * HWN + n0] = st;
    }
  }
}

// ------------------------------------------------------------------------------
extern "C" void kernel_launch(void* const* d_in, const int* in_sizes, int n_in,
                              void* d_out, int out_size, void* d_ws, size_t ws_size,
                              hipStream_t stream){
  const float* x     = (const float*)d_in[0];
  const float* gamma = (const float*)d_in[1];
  const float* beta  = (const float*)d_in[2];
  const float* Wq    = (const float*)d_in[3];
  const float* Wk    = (const float*)d_in[5];
  const float* Wv    = (const float*)d_in[7];
  const float* bv    = (const float*)d_in[8];
  const float* Wo    = (const float*)d_in[9];
  const float* bo    = (const float*)d_in[10];
  // bq/bk and GN-shift are per-row constants in Q/K -> cancel in softmax.
  // V path folded: out = N.x + b_eff; N = Wo.diag(1/16sq).S.diag(1/sk).Wv.diag(a)

  char* ws = (char*)d_ws;
  bf16*  xt    = (bf16*) (ws + 0);            // 64 MiB x^T bf16 [b][n][c]
  float* spart = (float*)(ws + 67108864);     // 64 MiB ES split-K partials
  bf16*  wqk   = (bf16*) (ws + 134217728);    // 2 MiB  W'qk [b][512][256]
  bf16*  wob   = (bf16*) (ws + 136314880);    // 128 KiB Wo bf16
  bf16*  wvt   = (bf16*) (ws + 136445952);    // 1 MiB  Wv'^T [b][c][d]
  float* S     = (float*)(ws + 137494528);    // 2 MiB  ES [b][c][d]
  bf16*  T1t   = (bf16*) (ws + 139591680);    // 1 MiB  scaled S^T [b][d][c]
  bf16*  Mbf   = (bf16*) (ws + 140640256);    // 1 MiB  M bf16 [b][o][d]
  bf16*  Nb    = (bf16*) (ws + 141688832);    // 1 MiB  N bf16 [b][o][c]
  float* sums  = (float*)(ws + 142737408);    // 16 KiB sq[2048], sk[2048]
  float* pst   = (float*)(ws + 142753792);    // 2 KiB  GN partial s/ss
  float* tvb   = (float*)(ws + 142755840);    // 8 KiB  Wv.sh + bv per batch
  float* beff  = (float*)(ws + 142764032);    // 8 KiB  effective out bias

  bf16* Qb = (bf16*)d_out;                    // E_Q rows 0..2047
  bf16* Kb = Qb + (size_t)2048 * HWN;         // E_K rows 2048..4095

  hipMemsetAsync(sums, 0, 4096 * sizeof(float), stream);
  hipMemsetAsync(pst,  0,  512 * sizeof(float), stream);

  xstats_t<<<dim3(256, 2, 8), dim3(256), 0, stream>>>(x, xt, pst);
  wprep<<<dim3(4, 8, 16), dim3(256), 0, stream>>>(Wq, Wk, Wv, Wo, gamma, beta,
                                                  bv, pst, wqk, wvt, wob, tvb);
  qk_gemm<<<dim3(128, 2, 8), dim3(256), 0, stream>>>(wqk, xt, Qb, sums);
  es_gemm<<<dim3(ESCH, 2, 8), dim3(256), 0, stream>>>(Kb, Qb, spart);
  reduce_S<<<dim3(512), dim3(256), 0, stream>>>(spart, S);
  scaleS_t<<<dim3(16, 8), dim3(256), 0, stream>>>(S, sums, T1t);
  // M[o][d] = sum_c Wo[o][c] . T1t[d][c]
  nt_gemm<<<dim3(2, 8), dim3(256), 0, stream>>>(T1t, wob, Mbf, 65536L, 0L, 65536L);
  beff_k<<<dim3(8), dim3(256), 0, stream>>>(Mbf, tvb, bo, beff);
  // N[o][c] = sum_d wvt[c][d] . M[o][d]
  nt_gemm<<<dim3(2, 8), dim3(256), 0, stream>>>(wvt, Mbf, Nb, 65536L, 65536L, 65536L);
  out_gemm<<<dim3(128, 8), dim3(256), 0, stream>>>(xt, Nb, beff, (float*)d_out);
}

// Round 19
// 277.873 us; speedup vs baseline: 1.0296x; 1.0119x over previous
//
#include <hip/hip_runtime.h>
#include <hip/hip_bf16.h>

#define BATCH 8
#define CHN 256
#define HWN 16384
#define EPSV 1e-6f
#define ESCH 32

typedef __attribute__((ext_vector_type(8))) short bf16x8;
typedef __attribute__((ext_vector_type(4))) short s16x4;
typedef __attribute__((ext_vector_type(4))) float f32x4;
typedef __hip_bfloat16 bf16;

__device__ __forceinline__ short f2s(float f){
  union { bf16 h; short s; } u; u.h = __float2bfloat16(f); return u.s;
}
__device__ __forceinline__ float s2f(short s){
  union { unsigned u; float f; } v; v.u = ((unsigned)(unsigned short)s) << 16; return v.f;
}
__device__ __forceinline__ void gload16(const bf16* g, bf16* l){
  __builtin_amdgcn_global_load_lds((const __attribute__((address_space(1))) void*)g,
                                   (__attribute__((address_space(3))) void*)l, 16, 0, 0);
}

// ---- K1 v9: read x once: GN stats + transpose x^T -> bf16 -------------------
// Group-aligned rows: thread's 8 c-rows = one GN group (c0 = t>>4), so stats
// accumulate in registers; ONE 4-step shfl reduce at the end (8 shfl vs 96).
// 16 unique plain sg stores (no atomics, no init barrier). LDS-pipe ops/thread
// drop ~2x; scatter writes become 4-way banked (1.58x, acceptable).
__global__ __launch_bounds__(256) void xstats_t(const float* __restrict__ x,
    bf16* __restrict__ xt, float* __restrict__ pst){
  int b = blockIdx.z, chh = blockIdx.y, n0 = blockIdx.x * 64;
  __shared__ char scr[64 * 256];              // [n][c' bf16], 16 KB swizzled
  __shared__ float sg[16], ssg[16];
  int t = threadIdx.x, lane = t & 63;
  const float* xb = x + (size_t)b * CHN * HWN + (size_t)(chh * 128) * HWN
                    + n0 + (t & 15) * 4;
  int c0 = t >> 4;                            // 0..15 == group within this half
  float s_acc = 0.f, ss_acc = 0.f;
  #pragma unroll
  for (int i = 0; i < 8; i++){
    int cl = c0 * 8 + i;                      // all 8 rows in group c0
    float4 v = *(const float4*)(xb + (size_t)cl * HWN);
    int nf = (t & 15) * 4;
    #pragma unroll
    for (int j = 0; j < 4; j++){
      int row = nf + j;
      float e = j == 0 ? v.x : (j == 1 ? v.y : (j == 2 ? v.z : v.w));
      int key = ((row >> 2) & 15) << 4;
      *(short*)(scr + row * 256 + ((cl * 2) ^ key)) = f2s(e);
    }
    s_acc  += v.x + v.y + v.z + v.w;
    ss_acc += v.x*v.x + v.y*v.y + v.z*v.z + v.w*v.w;
  }
  // reduce over the 16 consecutive lanes sharing c0
  s_acc  += __shfl_xor(s_acc, 1);  s_acc  += __shfl_xor(s_acc, 2);
  s_acc  += __shfl_xor(s_acc, 4);  s_acc  += __shfl_xor(s_acc, 8);
  ss_acc += __shfl_xor(ss_acc, 1); ss_acc += __shfl_xor(ss_acc, 2);
  ss_acc += __shfl_xor(ss_acc, 4); ss_acc += __shfl_xor(ss_acc, 8);
  if ((lane & 15) == 0){ sg[c0] = s_acc; ssg[c0] = ss_acc; }  // 16 unique writers
  __syncthreads();
  if (t < 16){
    atomicAdd(&pst[(b * 32 + chh * 16 + t) * 2],     sg[t]);
    atomicAdd(&pst[(b * 32 + chh * 16 + t) * 2 + 1], ssg[t]);
  }
  bf16* o = xt + (size_t)b * HWN * CHN + (size_t)n0 * CHN + chh * 128;
  #pragma unroll
  for (int p = 0; p < 4; p++){
    int idx = p * 256 + t;
    int n = idx >> 4, cq = idx & 15;
    int key = ((n >> 2) & 15) << 4;
    int4 v = *(const int4*)(scr + n * 256 + ((cq * 16) ^ key));
    *(int4*)&o[(size_t)n * CHN + cq * 8] = v;
  }
}

// ---- K2: folded weights. w=0,1: wqk = {Wq,Wk}.diag(a) ; w=2: wvt[c][d] =
//          Wv[d][c].a[c] + tvb = Wv.sh+bv ; w=3 (b==0): wob = bf16(Wo) -------
__global__ __launch_bounds__(256) void wprep(const float* __restrict__ Wq,
    const float* __restrict__ Wk, const float* __restrict__ Wv,
    const float* __restrict__ Wo, const float* __restrict__ gamma,
    const float* __restrict__ beta, const float* __restrict__ bv,
    const float* __restrict__ pst, bf16* __restrict__ wqk,
    bf16* __restrict__ wvt, bf16* __restrict__ wob, float* __restrict__ tvb){
  int w = blockIdx.x, b = blockIdx.y, rt = blockIdx.z, t = threadIdx.x;
  if (w == 3 && b != 0) return;
  const float* W = (w == 0) ? Wq : ((w == 1) ? Wk : ((w == 2) ? Wv : Wo));
  __shared__ float a_s[256], sh_s[256];
  __shared__ float racc[16];
  {
    int bg = b * 32 + (t >> 3);
    float m   = pst[bg * 2] * (1.f / 131072.f);
    float var = pst[bg * 2 + 1] * (1.f / 131072.f) - m * m;
    float r = rsqrtf(var + EPSV);
    float a = r * gamma[t];
    a_s[t] = a;
    sh_s[t] = beta[t] - m * a;
  }
  if (t < 16) racc[t] = 0.f;
  __syncthreads();
  float mya = a_s[t], mysh = sh_s[t];
  int lane = t & 63;
  bf16* wo_qk = wqk + ((size_t)b << 17) + ((size_t)w << 16);
  bf16* wo_v  = wvt + ((size_t)b << 16);
  #pragma unroll
  for (int jj = 0; jj < 16; jj++){
    int j = rt * 16 + jj;
    float wv_ = W[j * 256 + t];
    if (w < 2) wo_qk[j * 256 + t] = __float2bfloat16(wv_ * mya);
    else if (w == 3) wob[j * 256 + t] = __float2bfloat16(wv_);
    else {
      wo_v[(size_t)t * 256 + j] = __float2bfloat16(wv_ * mya);  // transposed
      float p = wv_ * mysh;
      p += __shfl_xor(p, 1);  p += __shfl_xor(p, 2);  p += __shfl_xor(p, 4);
      p += __shfl_xor(p, 8);  p += __shfl_xor(p, 16); p += __shfl_xor(p, 32);
      if (lane == 0) atomicAdd(&racc[jj], p);
    }
  }
  if (w == 2){
    __syncthreads();
    if (t < 16) tvb[b * 256 + rt * 16 + t] = racc[t] + bv[rt * 16 + t];
  }
}

// ---- K3: QK projection v3: 3-buffer counted-vmcnt pipeline ------------------
__global__ __launch_bounds__(256, 2) void qk_gemm(const bf16* __restrict__ wqk,
    const bf16* __restrict__ xt, bf16* __restrict__ Eout,
    float* __restrict__ sums){
  __shared__ bf16 lW[3][256 * 32];           // 48 KB
  __shared__ bf16 lX[3][128 * 32];           // 24 KB
  int t = threadIdx.x, nt = blockIdx.x, h = blockIdx.y, b = blockIdx.z;
  const bf16* Wb = wqk + ((size_t)b << 17) + ((size_t)h << 16);
  const bf16* Xb = xt + (size_t)b * HWN * CHN + (size_t)(nt * 128) * CHN;
  int lane = t & 63, w = t >> 6, r = lane & 15, kc = lane >> 4;
  f32x4 acc[8][4] = {};                      // [i: n frag][f: wrow frag]

  auto stage = [&](int buf, int k0){
    #pragma unroll
    for (int rep = 0; rep < 4; rep++){       // W: 256 rows -> 1024 chunks
      int c = t + rep * 256; int row = c >> 2;
      int off = ((c & 3) ^ ((c >> 3) & 3)) * 8;
      gload16(Wb + (size_t)row * 256 + k0 + off, &lW[buf][c * 8]);
    }
    #pragma unroll
    for (int rep = 0; rep < 2; rep++){       // X: 128 rows -> 512 chunks
      int c = t + rep * 256; int row = c >> 2;
      int off = ((c & 3) ^ ((c >> 3) & 3)) * 8;
      gload16(Xb + (size_t)row * 256 + k0 + off, &lX[buf][c * 8]);
    }
  };

  stage(0, 0);
  stage(1, 32);
  asm volatile("s_waitcnt vmcnt(6)" ::: "memory");   // buf0 complete
  __builtin_amdgcn_s_barrier();
  int slot8 = (kc ^ ((r >> 1) & 3)) * 8;
  #pragma unroll
  for (int ks = 0; ks < 8; ks++){
    int cur = ks % 3;
    if (ks < 6) stage((ks + 2) % 3, (ks + 2) * 32);
    bf16x8 af[8], bfv[4];
    #pragma unroll
    for (int i = 0; i < 8; i++)
      af[i] = *(const bf16x8*)&lX[cur][(i * 16 + r) * 32 + slot8];
    #pragma unroll
    for (int f = 0; f < 4; f++)
      bfv[f] = *(const bf16x8*)&lW[cur][(w * 64 + f * 16 + r) * 32 + slot8];
    #pragma unroll
    for (int i = 0; i < 8; i++)
      #pragma unroll
      for (int f = 0; f < 4; f++)
        acc[i][f] = __builtin_amdgcn_mfma_f32_16x16x32_bf16(af[i], bfv[f], acc[i][f], 0, 0, 0);
    if (ks < 7){
      if (ks < 6) asm volatile("s_waitcnt vmcnt(6)" ::: "memory");  // next buf done
      else        asm volatile("s_waitcnt vmcnt(0)" ::: "memory");
      __builtin_amdgcn_s_barrier();
    }
  }

  // epilogue: 2-pass LDS transpose (scr = 32 KB over lW[0..1]).
  char* scrB = (char*)&lW[0][0];
  float colp[4] = {0.f, 0.f, 0.f, 0.f};
  int base_row = (h ? 2048 : 0) + b * 256;
  #pragma unroll
  for (int p = 0; p < 2; p++){
    __syncthreads();
    #pragma unroll
    for (int fl = 0; fl < 2; fl++){
      int f = p * 2 + fl;
      int ri = w * 32 + fl * 16 + r;         // 0..127 compacted row
      int key = (ri & 7) << 4;
      #pragma unroll
      for (int i = 0; i < 8; i++){
        s16x4 pk;
        #pragma unroll
        for (int j = 0; j < 4; j++){
          float e = __expf(acc[i][f][j]);    // |q| small: no max-sub needed
          colp[f] += e;
          pk[j] = f2s(e);
        }
        *(s16x4*)(scrB + ri * 256 + ((i * 32 + kc * 8) ^ key)) = pk;
      }
    }
    __syncthreads();
    #pragma unroll
    for (int ps = 0; ps < 8; ps++){
      int c = t + ps * 256;
      int ri = c >> 4, q = c & 15;
      int key = (ri & 7) << 4;
      int4 v = *(const int4*)(scrB + ri * 256 + ((q * 16) ^ key));
      int wrow = (ri >> 5) * 64 + (p * 2 + ((ri >> 4) & 1)) * 16 + (ri & 15);
      *(int4*)&Eout[(size_t)(base_row + wrow) * HWN + nt * 128 + q * 8] = v;
    }
  }
  #pragma unroll
  for (int f = 0; f < 4; f++){
    float v = colp[f];
    v += __shfl_xor(v, 16); v += __shfl_xor(v, 32);
    if (lane < 16)
      atomicAdd(&sums[base_row + w * 64 + f * 16 + r], v);
  }
}

// ---- K5: ES split-K. A=E_K(128 rows), B=E_Q(256) ----------------------------
__global__ __launch_bounds__(256, 2) void es_gemm(const bf16* __restrict__ Ek,
    const bf16* __restrict__ Eq, float* __restrict__ spart){
  __shared__ bf16 lA[2][128 * 32];
  __shared__ bf16 lB[2][256 * 32];
  int t = threadIdx.x, ch = blockIdx.x, mt = blockIdx.y, z = blockIdx.z;
  const bf16* At = Ek + (size_t)z * 256 * HWN + (size_t)(mt * 128) * HWN + ch * 512;
  const bf16* Bt = Eq + (size_t)z * 256 * HWN + ch * 512;
  f32x4 acc[4][8] = {};
  int lane = t & 63, w = t >> 6, r = lane & 15, kc = lane >> 4;
  int ng = w >> 1, cg = w & 1;

  auto stage = [&](int buf, int k0){
    #pragma unroll
    for (int rep = 0; rep < 2; rep++){
      int c = t + rep * 256; int row = c >> 2;
      int off = ((c & 3) ^ ((c >> 3) & 3)) * 8;
      gload16(At + (size_t)row * HWN + k0 + off, &lA[buf][c * 8]);
    }
    #pragma unroll
    for (int rep = 0; rep < 4; rep++){
      int c = t + rep * 256; int row = c >> 2;
      int off = ((c & 3) ^ ((c >> 3) & 3)) * 8;
      gload16(Bt + (size_t)row * HWN + k0 + off, &lB[buf][c * 8]);
    }
  };

  stage(0, 0);
  __syncthreads();
  int cur = 0;
  int slot8 = (kc ^ ((r >> 1) & 3)) * 8;
  for (int ks = 0; ks < 16; ks++){
    if (ks < 15) stage(cur ^ 1, (ks + 1) * 32);
    bf16x8 af[4], bfv[8];
    #pragma unroll
    for (int i = 0; i < 4; i++)
      af[i] = *(const bf16x8*)&lA[cur][(ng * 64 + i * 16 + r) * 32 + slot8];
    #pragma unroll
    for (int f = 0; f < 8; f++)
      bfv[f] = *(const bf16x8*)&lB[cur][(cg * 128 + f * 16 + r) * 32 + slot8];
    #pragma unroll
    for (int i = 0; i < 4; i++)
      #pragma unroll
      for (int f = 0; f < 8; f++)
        acc[i][f] = __builtin_amdgcn_mfma_f32_16x16x32_bf16(af[i], bfv[f], acc[i][f], 0, 0, 0);
    __syncthreads();
    cur ^= 1;
  }

  float* sp = spart + ((size_t)(z * ESCH + ch) << 16);
  #pragma unroll
  for (int f = 0; f < 8; f++){
    int q = cg * 128 + f * 16 + r;
    #pragma unroll
    for (int i = 0; i < 4; i++){
      int k0i = mt * 128 + ng * 64 + i * 16 + kc * 4;
      *(f32x4*)&sp[q * 256 + k0i] = acc[i][f];
    }
  }
}

// ---- K6a: reduce split-K partials of ES (float4) ----------------------------
__global__ void reduce_S(const float* __restrict__ sp, float* __restrict__ S){
  size_t i = ((size_t)blockIdx.x * 256 + threadIdx.x) * 4;   // 8*65536 elems
  size_t b = i >> 16, cd = i & 65535;
  float4 s = {0.f, 0.f, 0.f, 0.f};
  #pragma unroll
  for (int ch = 0; ch < ESCH; ch++){
    float4 v = *(const float4*)&sp[((b * ESCH + ch) << 16) + cd];
    s.x += v.x; s.y += v.y; s.z += v.z; s.w += v.w;
  }
  *(float4*)&S[i] = s;
}

// ---- K6b: T1t[d][c] = S[c][d] / (16 sq[c] sk[d]) -> bf16 (LDS transpose) ----
__global__ __launch_bounds__(256) void scaleS_t(const float* __restrict__ S,
    const float* __restrict__ sums, bf16* __restrict__ T1t){
  int id = blockIdx.x, b = blockIdx.y;
  int dt = id >> 2, ct = id & 3, t = threadIdx.x;
  __shared__ float tile[64][65];
  __shared__ float sq_s[64], sk_s[64];
  if (t < 64)       sq_s[t]      = 0.0625f / sums[b * 256 + ct * 64 + t];
  else if (t < 128) sk_s[t - 64] = 1.f / sums[2048 + b * 256 + dt * 64 + (t - 64)];
  const float* Sb = S + ((size_t)b << 16);
  #pragma unroll
  for (int i = 0; i < 4; i++){
    int c_l = i * 16 + (t >> 4);
    int d_l0 = (t & 15) * 4;
    float4 v = *(const float4*)&Sb[(size_t)(ct * 64 + c_l) * 256 + dt * 64 + d_l0];
    tile[d_l0 + 0][c_l] = v.x;
    tile[d_l0 + 1][c_l] = v.y;
    tile[d_l0 + 2][c_l] = v.z;
    tile[d_l0 + 3][c_l] = v.w;
  }
  __syncthreads();
  bf16* Tb = T1t + ((size_t)b << 16);
  #pragma unroll
  for (int i = 0; i < 4; i++){
    int d_l = i * 16 + (t >> 4);
    int c_l0 = (t & 15) * 4;
    s16x4 pk;
    #pragma unroll
    for (int jj = 0; jj < 4; jj++)
      pk[jj] = f2s(tile[d_l][c_l0 + jj] * sq_s[c_l0 + jj] * sk_s[d_l]);
    *(s16x4*)&Tb[(size_t)(dt * 64 + d_l) * 256 + ct * 64 + c_l0] = pk;
  }
}

// ---- K6c: tiny NT MFMA GEMM: out[bcol][arow] = sum_k A[arow][k].B[bcol][k] --
__global__ __launch_bounds__(256, 2) void nt_gemm(const bf16* __restrict__ A,
    const bf16* __restrict__ B, bf16* __restrict__ out,
    long Asb, long Bsb, long Osb){
  __shared__ bf16 lA[2][256 * 32];
  __shared__ bf16 lB[2][128 * 32];
  int t = threadIdx.x, mt = blockIdx.x, b = blockIdx.y;
  const bf16* Ab = A + (size_t)b * Asb;
  const bf16* Bb = B + (size_t)b * Bsb + (size_t)(mt * 128) * 256;
  bf16* Ob = out + (size_t)b * Osb + (size_t)(mt * 128) * 256;
  int lane = t & 63, w = t >> 6, r = lane & 15, kc = lane >> 4;
  f32x4 acc[16][2] = {};

  auto stage = [&](int buf, int k0){
    #pragma unroll
    for (int rep = 0; rep < 4; rep++){           // 1024 chunks: full 256 rows
      int c = t + rep * 256; int row = c >> 2, off = (c & 3) * 8;
      gload16(Ab + (size_t)row * 256 + k0 + off, &lA[buf][c * 8]);
    }
    #pragma unroll
    for (int rep = 0; rep < 2; rep++){           // 512 chunks: full 128 rows
      int c = t + rep * 256; int row = c >> 2, off = (c & 3) * 8;
      gload16(Bb + (size_t)row * 256 + k0 + off, &lB[buf][c * 8]);
    }
  };

  stage(0, 0);
  __syncthreads();
  int cur = 0;
  for (int ks = 0; ks < 8; ks++){
    if (ks < 7) stage(cur ^ 1, (ks + 1) * 32);
    bf16x8 bfv[2];
    #pragma unroll
    for (int f = 0; f < 2; f++)
      bfv[f] = *(const bf16x8*)&lB[cur][(w * 32 + f * 16 + r) * 32 + kc * 8];
    #pragma unroll
    for (int i = 0; i < 16; i++){
      bf16x8 af = *(const bf16x8*)&lA[cur][(i * 16 + r) * 32 + kc * 8];
      acc[i][0] = __builtin_amdgcn_mfma_f32_16x16x32_bf16(af, bfv[0], acc[i][0], 0, 0, 0);
      acc[i][1] = __builtin_amdgcn_mfma_f32_16x16x32_bf16(af, bfv[1], acc[i][1], 0, 0, 0);
    }
    __syncthreads();
    cur ^= 1;
  }

  #pragma unroll
  for (int f = 0; f < 2; f++){
    int bcol = w * 32 + f * 16 + r;
    #pragma unroll
    for (int i = 0; i < 16; i++){
      s16x4 pk;
      #pragma unroll
      for (int j = 0; j < 4; j++) pk[j] = f2s(acc[i][f][j]);
      *(s16x4*)&Ob[(size_t)bcol * 256 + i * 16 + kc * 4] = pk;
    }
  }
}

// ---- K6d: beff[o] = M[o,:].tvb + bo ------------------------------------------
__global__ __launch_bounds__(256) void beff_k(const bf16* __restrict__ Mbf,
    const float* __restrict__ tvb, const float* __restrict__ bo,
    float* __restrict__ beff){
  int b = blockIdx.x, t = threadIdx.x;
  __shared__ float tv[256];
  tv[t] = tvb[b * 256 + t];
  __syncthreads();
  const bf16* Mr = Mbf + ((size_t)b << 16) + (size_t)t * 256;
  float s = 0.f;
  #pragma unroll
  for (int k = 0; k < 32; k++){
    bf16x8 v = *(const bf16x8*)&Mr[k * 8];
    #pragma unroll
    for (int e = 0; e < 8; e++) s += s2f(v[e]) * tv[k * 8 + e];
  }
  beff[b * 256 + t] = s + bo[t];
}

// ---- K7: out[o][n] = N . x^T + b_eff. A=xt(128 n), B=N(256 o) ---------------
__global__ __launch_bounds__(256, 2) void out_gemm(const bf16* __restrict__ xt,
    const bf16* __restrict__ Nb, const float* __restrict__ beff,
    float* __restrict__ out){
  __shared__ bf16 lA[2][128 * 32];
  __shared__ bf16 lB[2][256 * 32];
  int t = threadIdx.x, nt = blockIdx.x, z = blockIdx.y;
  const bf16* At = xt + (size_t)z * HWN * CHN + (size_t)(nt * 128) * CHN;
  const bf16* Bt = Nb + (size_t)z * 65536;
  f32x4 acc[4][8] = {};
  int lane = t & 63, w = t >> 6, r = lane & 15, kc = lane >> 4;
  int ng = w >> 1, cg = w & 1;

  auto stage = [&](int buf, int k0){
    #pragma unroll
    for (int rep = 0; rep < 2; rep++){
      int c = t + rep * 256; int row = c >> 2;
      int off = ((c & 3) ^ ((c >> 3) & 3)) * 8;
      gload16(At + (size_t)row * 256 + k0 + off, &lA[buf][c * 8]);
    }
    #pragma unroll
    for (int rep = 0; rep < 4; rep++){
      int c = t + rep * 256; int row = c >> 2;
      int off = ((c & 3) ^ ((c >> 3) & 3)) * 8;
      gload16(Bt + (size_t)row * 256 + k0 + off, &lB[buf][c * 8]);
    }
  };

  stage(0, 0);
  __syncthreads();
  int cur = 0;
  int slot8 = (kc ^ ((r >> 1) & 3)) * 8;
  for (int ks = 0; ks < 8; ks++){
    if (ks < 7) stage(cur ^ 1, (ks + 1) * 32);
    bf16x8 af[4], bfv[8];
    #pragma unroll
    for (int i = 0; i < 4; i++)
      af[i] = *(const bf16x8*)&lA[cur][(ng * 64 + i * 16 + r) * 32 + slot8];
    #pragma unroll
    for (int f = 0; f < 8; f++)
      bfv[f] = *(const bf16x8*)&lB[cur][(cg * 128 + f * 16 + r) * 32 + slot8];
    #pragma unroll
    for (int i = 0; i < 4; i++)
      #pragma unroll
      for (int f = 0; f < 8; f++)
        acc[i][f] = __builtin_amdgcn_mfma_f32_16x16x32_bf16(af[i], bfv[f], acc[i][f], 0, 0, 0);
    __syncthreads();
    cur ^= 1;
  }

  float* ob = out + (size_t)z * CHN * HWN;
  #pragma unroll
  for (int f = 0; f < 8; f++){
    int o = cg * 128 + f * 16 + r;
    float bb = beff[z * 256 + o];
    #pragma unroll
    for (int i = 0; i < 4; i++){
      int n0 = nt * 128 + ng * 64 + i * 16 + kc * 4;
      float4 st = { acc[i][f][0] + bb, acc[i][f][1] + bb,
                    acc[i][f][2] + bb, acc[i][f][3] + bb };
      *(float4*)&ob[(size_t)o * HWN + n0] = st;
    }
  }
}

// ------------------------------------------------------------------------------
extern "C" void kernel_launch(void* const* d_in, const int* in_sizes, int n_in,
                              void* d_out, int out_size, void* d_ws, size_t ws_size,
                              hipStream_t stream){
  const float* x     = (const float*)d_in[0];
  const float* gamma = (const float*)d_in[1];
  const float* beta  = (const float*)d_in[2];
  const float* Wq    = (const float*)d_in[3];
  const float* Wk    = (const float*)d_in[5];
  const float* Wv    = (const float*)d_in[7];
  const float* bv    = (const float*)d_in[8];
  const float* Wo    = (const float*)d_in[9];
  const float* bo    = (const float*)d_in[10];
  // bq/bk and GN-shift are per-row constants in Q/K -> cancel in softmax.
  // V path folded: out = N.x + b_eff; N = Wo.diag(1/16sq).S.diag(1/sk).Wv.diag(a)

  char* ws = (char*)d_ws;
  bf16*  xt    = (bf16*) (ws + 0);            // 64 MiB x^T bf16 [b][n][c]
  float* spart = (float*)(ws + 67108864);     // 64 MiB ES split-K partials
  bf16*  wqk   = (bf16*) (ws + 134217728);    // 2 MiB  W'qk [b][512][256]
  bf16*  wob   = (bf16*) (ws + 136314880);    // 128 KiB Wo bf16
  bf16*  wvt   = (bf16*) (ws + 136445952);    // 1 MiB  Wv'^T [b][c][d]
  float* S     = (float*)(ws + 137494528);    // 2 MiB  ES [b][c][d]
  bf16*  T1t   = (bf16*) (ws + 139591680);    // 1 MiB  scaled S^T [b][d][c]
  bf16*  Mbf   = (bf16*) (ws + 140640256);    // 1 MiB  M bf16 [b][o][d]
  bf16*  Nb    = (bf16*) (ws + 141688832);    // 1 MiB  N bf16 [b][o][c]
  float* sums  = (float*)(ws + 142737408);    // 16 KiB sq[2048], sk[2048]
  float* pst   = (float*)(ws + 142753792);    // 2 KiB  GN partial s/ss
  float* tvb   = (float*)(ws + 142755840);    // 8 KiB  Wv.sh + bv per batch
  float* beff  = (float*)(ws + 142764032);    // 8 KiB  effective out bias

  bf16* Qb = (bf16*)d_out;                    // E_Q rows 0..2047
  bf16* Kb = Qb + (size_t)2048 * HWN;         // E_K rows 2048..4095

  hipMemsetAsync(sums, 0, 4096 * sizeof(float), stream);
  hipMemsetAsync(pst,  0,  512 * sizeof(float), stream);

  xstats_t<<<dim3(256, 2, 8), dim3(256), 0, stream>>>(x, xt, pst);
  wprep<<<dim3(4, 8, 16), dim3(256), 0, stream>>>(Wq, Wk, Wv, Wo, gamma, beta,
                                                  bv, pst, wqk, wvt, wob, tvb);
  qk_gemm<<<dim3(128, 2, 8), dim3(256), 0, stream>>>(wqk, xt, Qb, sums);
  es_gemm<<<dim3(ESCH, 2, 8), dim3(256), 0, stream>>>(Kb, Qb, spart);
  reduce_S<<<dim3(512), dim3(256), 0, stream>>>(spart, S);
  scaleS_t<<<dim3(16, 8), dim3(256), 0, stream>>>(S, sums, T1t);
  // M[o][d] = sum_c Wo[o][c] . T1t[d][c]
  nt_gemm<<<dim3(2, 8), dim3(256), 0, stream>>>(T1t, wob, Mbf, 65536L, 0L, 65536L);
  beff_k<<<dim3(8), dim3(256), 0, stream>>>(Mbf, tvb, bo, beff);
  // N[o][c] = sum_d wvt[c][d] . M[o][d]
  nt_gemm<<<dim3(2, 8), dim3(256), 0, stream>>>(wvt, Mbf, Nb, 65536L, 65536L, 65536L);
  out_gemm<<<dim3(128, 8), dim3(256), 0, stream>>>(xt, Nb, beff, (float*)d_out);
}